// Round 6
// baseline (452.539 us; speedup 1.0000x reference)
//
#include <hip/hip_runtime.h>

#define BB 4
#define DD 4096
#define FF 128
#define SLOPE 0.2f

typedef float f32x4 __attribute__((ext_vector_type(4)));
typedef int   i32x4 __attribute__((ext_vector_type(4)));
typedef short bf16x8 __attribute__((ext_vector_type(8)));

// LDS-only barrier: ds_writes visible across waves, but global loads/stores
// stay in flight (no vmcnt drain, unlike __syncthreads()).
#define SOFT_BARRIER() do { \
  asm volatile("s_waitcnt lgkmcnt(0)" ::: "memory"); \
  __builtin_amdgcn_s_barrier(); \
} while (0)

__device__ __forceinline__ unsigned short f2bf(float v) {
  union { float f; unsigned u; } c; c.f = v;
  unsigned r = c.u + 0x7FFFu + ((c.u >> 16) & 1u);
  return (unsigned short)(r >> 16);
}

// Kernel A: Wh = x@W (f32 regs) -> WhT bf16 [B][F][D]; fs, ft (f32);
// mbpart[wg] = max(0, max over this wg's 64 rows of ft)  (no memset needed)
__global__ __launch_bounds__(256) void kA(
    const float* __restrict__ x, const float* __restrict__ W,
    const float* __restrict__ a_src, const float* __restrict__ a_tgt,
    unsigned short* __restrict__ WhT, float* __restrict__ fs,
    float* __restrict__ ft, float* __restrict__ mbpart)
{
  __shared__ __align__(16) float Ws[128 * 128];
  __shared__ __align__(16) float xs[64 * 128];     // reused as reduction scratch
  __shared__ unsigned short st[128 * 66];
  const int t = threadIdx.x;
  const int wg = blockIdx.x;            // 256 wgs x 64 rows
  const int row0 = wg * 64;             // flat row in [0, B*D)
  const int b = row0 / DD;
  const int i_in_b = row0 % DD;

  for (int i = t * 4; i < 128 * 128; i += 1024)
    *(float4*)&Ws[i] = *(const float4*)&W[i];
  for (int i = t * 4; i < 64 * 128; i += 1024)
    *(float4*)&xs[i] = *(const float4*)&x[(size_t)row0 * FF + i];
  __syncthreads();

  const int fg = t & 31, rg = t >> 5;
  const int f0 = fg * 4, r0 = rg * 8;
  float acc[8][4];
  #pragma unroll
  for (int a = 0; a < 8; ++a) acc[a][0] = acc[a][1] = acc[a][2] = acc[a][3] = 0.f;
  for (int k = 0; k < 128; ++k) {
    float4 wq = *(const float4*)&Ws[k * 128 + f0];
    #pragma unroll
    for (int rr = 0; rr < 8; ++rr) {
      float xv = xs[(r0 + rr) * 128 + k];
      acc[rr][0] += xv * wq.x; acc[rr][1] += xv * wq.y;
      acc[rr][2] += xv * wq.z; acc[rr][3] += xv * wq.w;
    }
  }
  __syncthreads();   // done reading xs; reuse as reduction scratch
  float* red_s = xs;             // [64][33]
  float* red_t = xs + 64 * 33;   // [64][33]
  float4 as4 = *(const float4*)&a_src[f0];
  float4 at4 = *(const float4*)&a_tgt[f0];
  #pragma unroll
  for (int rr = 0; rr < 8; ++rr) {
    float ps = acc[rr][0]*as4.x + acc[rr][1]*as4.y + acc[rr][2]*as4.z + acc[rr][3]*as4.w;
    float pt = acc[rr][0]*at4.x + acc[rr][1]*at4.y + acc[rr][2]*at4.z + acc[rr][3]*at4.w;
    red_s[(r0 + rr) * 33 + fg] = ps;
    red_t[(r0 + rr) * 33 + fg] = pt;
    st[(f0 + 0) * 66 + r0 + rr] = f2bf(acc[rr][0]);
    st[(f0 + 1) * 66 + r0 + rr] = f2bf(acc[rr][1]);
    st[(f0 + 2) * 66 + r0 + rr] = f2bf(acc[rr][2]);
    st[(f0 + 3) * 66 + r0 + rr] = f2bf(acc[rr][3]);
  }
  __syncthreads();
  if (t < 64) {
    float s = 0.f, tt = 0.f;
    #pragma unroll
    for (int q = 0; q < 32; ++q) { s += red_s[t * 33 + q]; tt += red_t[t * 33 + q]; }
    fs[row0 + t] = s;
    ft[row0 + t] = tt;
    float m = fmaxf(0.f, tt);
    #pragma unroll
    for (int s2 = 1; s2 < 64; s2 <<= 1) m = fmaxf(m, __shfl_xor(m, s2));
    if (t == 0) mbpart[wg] = m;        // unconditional write: no init required
  }
  // WhT bf16 writeout (coalesced per 64-wide row chunks)
  for (int p = 0; p < 32; ++p) {
    int idx = p * 256 + t;
    int f = idx >> 6, rl = idx & 63;
    WhT[((size_t)b * FF + f) * DD + i_in_b + rl] = st[f * 66 + rl];
  }
}

// Kernel F (fused): 16 rows/wg, 8 waves.
// Pass 1: each wave streams its 2 adj rows once (non-temporal) -> LDS bitmask +
//         row sums (wave-local, no barrier).
// Pass 2: 16-chunk pipeline with SOFT barriers (LDS-only): B-prefetch stays in
//         flight across the barrier; attn stores (non-temporal) never drained.
__global__ __launch_bounds__(512, 4) void kF(
    const int* __restrict__ adj, const float* __restrict__ fs,
    const float* __restrict__ ft, const float* __restrict__ mbpart,
    const unsigned short* __restrict__ WhT, const float* __restrict__ bias,
    float* __restrict__ hout, float* __restrict__ attn)
{
  __shared__ __align__(16) unsigned short p_lds[2][16 * 256];  // 16 KB, XOR-swizzled
  __shared__ __align__(16) unsigned int mlds[16 * 128];        // 8 KB row bitmasks
  const int t = threadIdx.x;
  const int w = t >> 6, l = t & 63;
  int bid = blockIdx.x;
  bid = (bid & 7) * 128 + (bid >> 3);   // bijective XCD swizzle (nwg=1024)
  const int b = bid >> 8;
  const int i0 = (bid & 255) << 4;
  // per-batch ft upper bound from kA partials
  float mbv = mbpart[b * 64 + l];
  #pragma unroll
  for (int s = 1; s < 64; s <<= 1) mbv = fmaxf(mbv, __shfl_xor(mbv, s));
  const int r0 = 2 * w, r1 = r0 + 1;
  const float fs0 = fs[b * DD + i0 + r0], fs1 = fs[b * DD + i0 + r1];
  const float M0 = fmaxf(0.f, fs0 + mbv), M1 = fmaxf(0.f, fs1 + mbv);

  // ---- Pass 1: stream adj rows r0,r1 (lane owns 64 contiguous j) ----
  const int* a0p = adj + (size_t)(b * DD + i0 + r0) * DD + l * 64;
  const int* a1p = a0p + DD;
  const float* ftl = ft + (size_t)b * DD + l * 64;
  float sum0 = 0.f, sum1 = 0.f;
  unsigned lo0 = 0u, hi0 = 0u, lo1 = 0u, hi1 = 0u;
  #pragma unroll
  for (int q = 0; q < 4; ++q) {
    unsigned bits0 = 0u, bits1 = 0u;
    #pragma unroll
    for (int u = 0; u < 4; ++u) {
      const int o = q * 16 + u * 4;
      i32x4 a = __builtin_nontemporal_load((const i32x4*)(a0p + o));
      i32x4 c = __builtin_nontemporal_load((const i32x4*)(a1p + o));
      float4 f = *(const float4*)(ftl + o);
      float e;
      e = fs0 + f.x; e = e > 0.f ? e : SLOPE * e; e = a.x ? e : 0.f; sum0 += __expf(e - M0);
      e = fs0 + f.y; e = e > 0.f ? e : SLOPE * e; e = a.y ? e : 0.f; sum0 += __expf(e - M0);
      e = fs0 + f.z; e = e > 0.f ? e : SLOPE * e; e = a.z ? e : 0.f; sum0 += __expf(e - M0);
      e = fs0 + f.w; e = e > 0.f ? e : SLOPE * e; e = a.w ? e : 0.f; sum0 += __expf(e - M0);
      e = fs1 + f.x; e = e > 0.f ? e : SLOPE * e; e = c.x ? e : 0.f; sum1 += __expf(e - M1);
      e = fs1 + f.y; e = e > 0.f ? e : SLOPE * e; e = c.y ? e : 0.f; sum1 += __expf(e - M1);
      e = fs1 + f.z; e = e > 0.f ? e : SLOPE * e; e = c.z ? e : 0.f; sum1 += __expf(e - M1);
      e = fs1 + f.w; e = e > 0.f ? e : SLOPE * e; e = c.w ? e : 0.f; sum1 += __expf(e - M1);
      bits0 |= (a.x ? 1u : 0u) << (u * 4 + 0);
      bits0 |= (a.y ? 1u : 0u) << (u * 4 + 1);
      bits0 |= (a.z ? 1u : 0u) << (u * 4 + 2);
      bits0 |= (a.w ? 1u : 0u) << (u * 4 + 3);
      bits1 |= (c.x ? 1u : 0u) << (u * 4 + 0);
      bits1 |= (c.y ? 1u : 0u) << (u * 4 + 1);
      bits1 |= (c.z ? 1u : 0u) << (u * 4 + 2);
      bits1 |= (c.w ? 1u : 0u) << (u * 4 + 3);
    }
    if      (q == 0) { lo0  = bits0;       lo1  = bits1;       }
    else if (q == 1) { lo0 |= bits0 << 16; lo1 |= bits1 << 16; }
    else if (q == 2) { hi0  = bits0;       hi1  = bits1;       }
    else             { hi0 |= bits0 << 16; hi1 |= bits1 << 16; }
  }
  { uint2 mv; mv.x = lo0; mv.y = hi0; *(uint2*)&mlds[r0 * 128 + l * 2] = mv; }
  { uint2 mv; mv.x = lo1; mv.y = hi1; *(uint2*)&mlds[r1 * 128 + l * 2] = mv; }
  #pragma unroll
  for (int s = 1; s < 64; s <<= 1) {
    sum0 += __shfl_xor(sum0, s);
    sum1 += __shfl_xor(sum1, s);
  }
  const float inv0 = 1.0f / sum0;
  const float inv1 = 1.0f / sum1;

  // ---- Pass 2: 16-chunk pipeline (soft barriers only) ----
  float* arow0 = attn + (size_t)b * DD * DD + (size_t)(i0 + r0) * DD;
  float* arow1 = arow0 + DD;
  const unsigned sw0 = (unsigned)(r0 & 7) << 4;
  const unsigned sw1 = (unsigned)(r1 & 7) << 4;
  const int f0 = w * 16;
  const int c15 = l & 15;
  const int kg = l >> 4;
  const unsigned abase = (unsigned)c15 * 512u + (unsigned)kg * 16u;
  const unsigned asw = (unsigned)(c15 & 7) << 4;
  const unsigned short* wrow = WhT + ((size_t)b * FF + f0 + c15) * DD + kg * 8;
  const int jl = l * 4;
  const unsigned mshift = (unsigned)(jl & 31);
  const unsigned w0base = (unsigned)r0 * 128u + (unsigned)(jl >> 5);
  const unsigned w1base = (unsigned)r1 * 128u + (unsigned)(jl >> 5);
  const unsigned o0 = ((unsigned)r0 * 512u + (unsigned)jl * 2u) ^ sw0;
  const unsigned o1 = ((unsigned)r1 * 512u + (unsigned)jl * 2u) ^ sw1;
  f32x4 acc0 = {0.f, 0.f, 0.f, 0.f}, acc1 = {0.f, 0.f, 0.f, 0.f};

  #pragma unroll 2
  for (int c = 0; c < 16; ++c) {
    const int cb = c & 1;
    const int j = c * 256 + jl;
    // B prefetch for this chunk's 8 k-steps; with soft barriers these stay in
    // flight until their MFMA use (vmcnt counted at use, not at the barrier).
    bf16x8 Bv[8];
    #pragma unroll
    for (int u = 0; u < 8; ++u)
      Bv[u] = *(const bf16x8*)&wrow[(size_t)(c * 8 + u) * 32];
    float4 f4 = *(const float4*)(ft + (size_t)b * DD + j);
    unsigned n0 = (mlds[w0base + (unsigned)c * 8u] >> mshift) & 0xFu;
    unsigned n1 = (mlds[w1base + (unsigned)c * 8u] >> mshift) & 0xFu;
    float e;
    e = fs0 + f4.x; e = e > 0.f ? e : SLOPE * e; e = (n0 & 1u) ? e : 0.f; float p00 = __expf(e - M0) * inv0;
    e = fs0 + f4.y; e = e > 0.f ? e : SLOPE * e; e = (n0 & 2u) ? e : 0.f; float p01 = __expf(e - M0) * inv0;
    e = fs0 + f4.z; e = e > 0.f ? e : SLOPE * e; e = (n0 & 4u) ? e : 0.f; float p02 = __expf(e - M0) * inv0;
    e = fs0 + f4.w; e = e > 0.f ? e : SLOPE * e; e = (n0 & 8u) ? e : 0.f; float p03 = __expf(e - M0) * inv0;
    e = fs1 + f4.x; e = e > 0.f ? e : SLOPE * e; e = (n1 & 1u) ? e : 0.f; float p10 = __expf(e - M1) * inv1;
    e = fs1 + f4.y; e = e > 0.f ? e : SLOPE * e; e = (n1 & 2u) ? e : 0.f; float p11 = __expf(e - M1) * inv1;
    e = fs1 + f4.z; e = e > 0.f ? e : SLOPE * e; e = (n1 & 4u) ? e : 0.f; float p12 = __expf(e - M1) * inv1;
    e = fs1 + f4.w; e = e > 0.f ? e : SLOPE * e; e = (n1 & 8u) ? e : 0.f; float p13 = __expf(e - M1) * inv1;
    f32x4 v0; v0.x = p00; v0.y = p01; v0.z = p02; v0.w = p03;
    f32x4 v1; v1.x = p10; v1.y = p11; v1.z = p12; v1.w = p13;
    __builtin_nontemporal_store(v0, (f32x4*)(arow0 + j));
    __builtin_nontemporal_store(v1, (f32x4*)(arow1 + j));
    ushort4 q0; q0.x = f2bf(p00); q0.y = f2bf(p01); q0.z = f2bf(p02); q0.w = f2bf(p03);
    ushort4 q1; q1.x = f2bf(p10); q1.y = f2bf(p11); q1.z = f2bf(p12); q1.w = f2bf(p13);
    *(ushort4*)((char*)&p_lds[cb][0] + o0) = q0;
    *(ushort4*)((char*)&p_lds[cb][0] + o1) = q1;
    SOFT_BARRIER();
    // 8 MFMA k-steps on this chunk (A from LDS, B prefetched above)
    #pragma unroll
    for (int u = 0; u < 8; ++u) {
      unsigned ao = (abase + (unsigned)u * 64u) ^ asw;
      bf16x8 A = *(const bf16x8*)((const char*)&p_lds[cb][0] + ao);
      if (u & 1) acc1 = __builtin_amdgcn_mfma_f32_16x16x32_bf16(A, Bv[u], acc1, 0, 0, 0);
      else       acc0 = __builtin_amdgcn_mfma_f32_16x16x32_bf16(A, Bv[u], acc0, 0, 0, 0);
    }
  }
  f32x4 acc = acc0 + acc1;
  const float bv = bias[f0 + c15];
  #pragma unroll
  for (int q = 0; q < 4; ++q) {
    int orow = kg * 4 + q;       // C/D: row = (lane>>4)*4 + reg
    hout[((size_t)b * DD + i0 + orow) * FF + f0 + c15] = acc[q] + bv;
  }
}

extern "C" void kernel_launch(void* const* d_in, const int* in_sizes, int n_in,
                              void* d_out, int out_size, void* d_ws, size_t ws_size,
                              hipStream_t stream) {
  const float* x     = (const float*)d_in[0];
  const int*   adj   = (const int*)d_in[1];
  const float* W     = (const float*)d_in[2];
  const float* a_src = (const float*)d_in[3];
  const float* a_tgt = (const float*)d_in[4];
  const float* bias  = (const float*)d_in[5];
  char* ws = (char*)d_ws;
  unsigned short* WhT    = (unsigned short*)ws;         // 4 MB
  float*        fs     = (float*)(ws + 4194304);        // 64 KB
  float*        ft     = (float*)(ws + 4259840);        // 64 KB
  float*        mbpart = (float*)(ws + 4325376);        // 1 KB
  float* hout = (float*)d_out;                          // [B][D][F]
  float* attn = hout + (size_t)BB * DD * FF;            // [B][D][D]
  kA<<<256, 256, 0, stream>>>(x, W, a_src, a_tgt, WhT, fs, ft, mbpart);
  kF<<<1024, 512, 0, stream>>>(adj, fs, ft, mbpart, WhT, bias, hout, attn);
}

// Round 7
// 399.202 us; speedup vs baseline: 1.1336x; 1.1336x over previous
//
#include <hip/hip_runtime.h>

#define BB 4
#define DD 4096
#define FF 128
#define SLOPE 0.2f

typedef float f32x4 __attribute__((ext_vector_type(4)));
typedef int   i32x4 __attribute__((ext_vector_type(4)));
typedef short bf16x8 __attribute__((ext_vector_type(8)));

// LDS-only barrier: ds_writes visible across waves, but global loads/stores
// stay in flight (no vmcnt drain, unlike __syncthreads()).
#define SOFT_BARRIER() do { \
  asm volatile("s_waitcnt lgkmcnt(0)" ::: "memory"); \
  __builtin_amdgcn_s_barrier(); \
} while (0)

__device__ __forceinline__ unsigned short f2bf(float v) {
  union { float f; unsigned u; } c; c.f = v;
  unsigned r = c.u + 0x7FFFu + ((c.u >> 16) & 1u);
  return (unsigned short)(r >> 16);
}

// Kernel A: Wh = x@W (f32 regs) -> WhT bf16 [B][F][D]; fs, ft (f32);
// mbpart[wg] = max(0, max over this wg's 64 rows of ft)  (no memset needed)
__global__ __launch_bounds__(256) void kA(
    const float* __restrict__ x, const float* __restrict__ W,
    const float* __restrict__ a_src, const float* __restrict__ a_tgt,
    unsigned short* __restrict__ WhT, float* __restrict__ fs,
    float* __restrict__ ft, float* __restrict__ mbpart)
{
  __shared__ __align__(16) float Ws[128 * 128];
  __shared__ __align__(16) float xs[64 * 128];     // reused as reduction scratch
  __shared__ unsigned short st[128 * 66];
  const int t = threadIdx.x;
  const int wg = blockIdx.x;            // 256 wgs x 64 rows
  const int row0 = wg * 64;             // flat row in [0, B*D)
  const int b = row0 / DD;
  const int i_in_b = row0 % DD;

  for (int i = t * 4; i < 128 * 128; i += 1024)
    *(float4*)&Ws[i] = *(const float4*)&W[i];
  for (int i = t * 4; i < 64 * 128; i += 1024)
    *(float4*)&xs[i] = *(const float4*)&x[(size_t)row0 * FF + i];
  __syncthreads();

  const int fg = t & 31, rg = t >> 5;
  const int f0 = fg * 4, r0 = rg * 8;
  float acc[8][4];
  #pragma unroll
  for (int a = 0; a < 8; ++a) acc[a][0] = acc[a][1] = acc[a][2] = acc[a][3] = 0.f;
  for (int k = 0; k < 128; ++k) {
    float4 wq = *(const float4*)&Ws[k * 128 + f0];
    #pragma unroll
    for (int rr = 0; rr < 8; ++rr) {
      float xv = xs[(r0 + rr) * 128 + k];
      acc[rr][0] += xv * wq.x; acc[rr][1] += xv * wq.y;
      acc[rr][2] += xv * wq.z; acc[rr][3] += xv * wq.w;
    }
  }
  __syncthreads();   // done reading xs; reuse as reduction scratch
  float* red_s = xs;             // [64][33]
  float* red_t = xs + 64 * 33;   // [64][33]
  float4 as4 = *(const float4*)&a_src[f0];
  float4 at4 = *(const float4*)&a_tgt[f0];
  #pragma unroll
  for (int rr = 0; rr < 8; ++rr) {
    float ps = acc[rr][0]*as4.x + acc[rr][1]*as4.y + acc[rr][2]*as4.z + acc[rr][3]*as4.w;
    float pt = acc[rr][0]*at4.x + acc[rr][1]*at4.y + acc[rr][2]*at4.z + acc[rr][3]*at4.w;
    red_s[(r0 + rr) * 33 + fg] = ps;
    red_t[(r0 + rr) * 33 + fg] = pt;
    st[(f0 + 0) * 66 + r0 + rr] = f2bf(acc[rr][0]);
    st[(f0 + 1) * 66 + r0 + rr] = f2bf(acc[rr][1]);
    st[(f0 + 2) * 66 + r0 + rr] = f2bf(acc[rr][2]);
    st[(f0 + 3) * 66 + r0 + rr] = f2bf(acc[rr][3]);
  }
  __syncthreads();
  if (t < 64) {
    float s = 0.f, tt = 0.f;
    #pragma unroll
    for (int q = 0; q < 32; ++q) { s += red_s[t * 33 + q]; tt += red_t[t * 33 + q]; }
    fs[row0 + t] = s;
    ft[row0 + t] = tt;
    float m = fmaxf(0.f, tt);
    #pragma unroll
    for (int s2 = 1; s2 < 64; s2 <<= 1) m = fmaxf(m, __shfl_xor(m, s2));
    if (t == 0) mbpart[wg] = m;        // unconditional write: no init required
  }
  // WhT bf16 writeout (coalesced per 64-wide row chunks)
  for (int p = 0; p < 32; ++p) {
    int idx = p * 256 + t;
    int f = idx >> 6, rl = idx & 63;
    WhT[((size_t)b * FF + f) * DD + i_in_b + rl] = st[f * 66 + rl];
  }
}

// Kernel F (fused): 32 rows/wg, 8 waves, 512 wgs (2 wg/CU).
// Pass 1: each wave streams its 4 adj rows once (nt loads) -> LDS bitmask +
//         row sums (wave-local, no barrier).
// Pass 2: 16-chunk pipeline, soft barriers. Each wave: one B fragment set
//         feeds TWO 16-row m-tiles (B reuse x2 -> WhT traffic halves).
__global__ __launch_bounds__(512, 4) void kF(
    const int* __restrict__ adj, const float* __restrict__ fs,
    const float* __restrict__ ft, const float* __restrict__ mbpart,
    const unsigned short* __restrict__ WhT, const float* __restrict__ bias,
    float* __restrict__ hout, float* __restrict__ attn)
{
  __shared__ __align__(16) unsigned short p_lds[2][32 * 256];  // 32 KB, XOR-swizzled
  __shared__ __align__(16) unsigned int mlds[32 * 128];        // 16 KB row bitmasks
  const int t = threadIdx.x;
  const int w = t >> 6, l = t & 63;
  const int hw = blockIdx.x;
  const int bid = (hw & 7) * 64 + (hw >> 3);   // bijective XCD swizzle (nwg=512)
  const int b = bid >> 7;
  const int i0 = (bid & 127) << 5;             // 32 rows per wg
  // per-batch ft upper bound from kA partials
  float mbv = mbpart[b * 64 + l];
  #pragma unroll
  for (int s = 1; s < 64; s <<= 1) mbv = fmaxf(mbv, __shfl_xor(mbv, s));
  const int rbase = 4 * w;                     // wave owns rows rbase..rbase+3
  float fsr[4], Mr[4];
  #pragma unroll
  for (int m = 0; m < 4; ++m) {
    fsr[m] = fs[b * DD + i0 + rbase + m];
    Mr[m] = fmaxf(0.f, fsr[m] + mbv);
  }

  // ---- Pass 1: stream 4 adj rows (lane owns 64 contiguous j; nt loads) ----
  const int* ap[4];
  #pragma unroll
  for (int m = 0; m < 4; ++m)
    ap[m] = adj + (size_t)(b * DD + i0 + rbase + m) * DD + l * 64;
  const float* ftl = ft + (size_t)b * DD + l * 64;
  float sum[4] = {0.f, 0.f, 0.f, 0.f};
  unsigned lo[4] = {0u, 0u, 0u, 0u}, hi[4] = {0u, 0u, 0u, 0u};
  #pragma unroll
  for (int q = 0; q < 4; ++q) {
    unsigned bits[4] = {0u, 0u, 0u, 0u};
    #pragma unroll
    for (int u = 0; u < 4; ++u) {
      const int o = q * 16 + u * 4;
      float4 f = *(const float4*)(ftl + o);
      #pragma unroll
      for (int m = 0; m < 4; ++m) {
        i32x4 a = __builtin_nontemporal_load((const i32x4*)(ap[m] + o));
        float e;
        e = fsr[m] + f.x; e = e > 0.f ? e : SLOPE * e; e = a.x ? e : 0.f; sum[m] += __expf(e - Mr[m]);
        e = fsr[m] + f.y; e = e > 0.f ? e : SLOPE * e; e = a.y ? e : 0.f; sum[m] += __expf(e - Mr[m]);
        e = fsr[m] + f.z; e = e > 0.f ? e : SLOPE * e; e = a.z ? e : 0.f; sum[m] += __expf(e - Mr[m]);
        e = fsr[m] + f.w; e = e > 0.f ? e : SLOPE * e; e = a.w ? e : 0.f; sum[m] += __expf(e - Mr[m]);
        bits[m] |= (a.x ? 1u : 0u) << (u * 4 + 0);
        bits[m] |= (a.y ? 1u : 0u) << (u * 4 + 1);
        bits[m] |= (a.z ? 1u : 0u) << (u * 4 + 2);
        bits[m] |= (a.w ? 1u : 0u) << (u * 4 + 3);
      }
    }
    #pragma unroll
    for (int m = 0; m < 4; ++m) {
      if      (q == 0) lo[m]  = bits[m];
      else if (q == 1) lo[m] |= bits[m] << 16;
      else if (q == 2) hi[m]  = bits[m];
      else             hi[m] |= bits[m] << 16;
    }
  }
  #pragma unroll
  for (int m = 0; m < 4; ++m) {
    uint2 mv; mv.x = lo[m]; mv.y = hi[m];
    *(uint2*)&mlds[(rbase + m) * 128 + l * 2] = mv;
  }
  float inv[4];
  #pragma unroll
  for (int m = 0; m < 4; ++m) {
    #pragma unroll
    for (int s = 1; s < 64; s <<= 1) sum[m] += __shfl_xor(sum[m], s);
    inv[m] = 1.0f / sum[m];
  }

  // ---- Pass 2: 16-chunk pipeline (soft barriers only) ----
  float* arow[4];
  unsigned o_[4], wb_[4];
  const int jl = l * 4;
  const unsigned mshift = (unsigned)(jl & 31);
  #pragma unroll
  for (int m = 0; m < 4; ++m) {
    const int r = rbase + m;
    arow[m] = attn + (size_t)b * DD * DD + (size_t)(i0 + r) * DD;
    o_[m] = (((unsigned)r * 512u) + (unsigned)jl * 2u) ^ ((unsigned)(r & 7) << 4);
    wb_[m] = (unsigned)r * 128u + (unsigned)(jl >> 5);
  }
  const int f0 = w * 16;
  const int c15 = l & 15;
  const int kg = l >> 4;
  const unsigned abase = (unsigned)c15 * 512u + (unsigned)kg * 16u;
  const unsigned asw = (unsigned)(c15 & 7) << 4;
  const unsigned short* wrow = WhT + ((size_t)b * FF + f0 + c15) * DD + kg * 8;
  f32x4 accA = {0.f, 0.f, 0.f, 0.f}, accB = {0.f, 0.f, 0.f, 0.f};

  #pragma unroll 2
  for (int c = 0; c < 16; ++c) {
    const int cb = c & 1;
    const int j = c * 256 + jl;
    // B prefetch for this chunk's 8 k-steps; soft barriers keep them in
    // flight until their MFMA use.
    bf16x8 Bv[8];
    #pragma unroll
    for (int u = 0; u < 8; ++u)
      Bv[u] = *(const bf16x8*)&wrow[(size_t)(c * 8 + u) * 32];
    float4 f4 = *(const float4*)(ft + (size_t)b * DD + j);
    #pragma unroll
    for (int m = 0; m < 4; ++m) {
      unsigned n = (mlds[wb_[m] + (unsigned)c * 8u] >> mshift) & 0xFu;
      float e, p0, p1, p2, p3;
      e = fsr[m] + f4.x; e = e > 0.f ? e : SLOPE * e; e = (n & 1u) ? e : 0.f; p0 = __expf(e - Mr[m]) * inv[m];
      e = fsr[m] + f4.y; e = e > 0.f ? e : SLOPE * e; e = (n & 2u) ? e : 0.f; p1 = __expf(e - Mr[m]) * inv[m];
      e = fsr[m] + f4.z; e = e > 0.f ? e : SLOPE * e; e = (n & 4u) ? e : 0.f; p2 = __expf(e - Mr[m]) * inv[m];
      e = fsr[m] + f4.w; e = e > 0.f ? e : SLOPE * e; e = (n & 8u) ? e : 0.f; p3 = __expf(e - Mr[m]) * inv[m];
      f32x4 v; v.x = p0; v.y = p1; v.z = p2; v.w = p3;
      *(f32x4*)(arow[m] + j) = v;                       // normal store (L2)
      ushort4 qv; qv.x = f2bf(p0); qv.y = f2bf(p1); qv.z = f2bf(p2); qv.w = f2bf(p3);
      *(ushort4*)((char*)&p_lds[cb][0] + o_[m]) = qv;
    }
    SOFT_BARRIER();
    // 16 MFMA k-steps: two 16-row m-tiles share Bv (two independent chains)
    #pragma unroll
    for (int u = 0; u < 8; ++u) {
      unsigned ao0 = (abase + (unsigned)u * 64u) ^ asw;
      bf16x8 A0 = *(const bf16x8*)((const char*)&p_lds[cb][0] + ao0);
      bf16x8 A1 = *(const bf16x8*)((const char*)&p_lds[cb][0] + ao0 + 8192u);
      accA = __builtin_amdgcn_mfma_f32_16x16x32_bf16(A0, Bv[u], accA, 0, 0, 0);
      accB = __builtin_amdgcn_mfma_f32_16x16x32_bf16(A1, Bv[u], accB, 0, 0, 0);
    }
  }
  const float bv = bias[f0 + c15];
  #pragma unroll
  for (int q = 0; q < 4; ++q) {
    int orow = kg * 4 + q;       // C/D: row = (lane>>4)*4 + reg
    hout[((size_t)b * DD + i0 + orow) * FF + f0 + c15] = accA[q] + bv;
    hout[((size_t)b * DD + i0 + 16 + orow) * FF + f0 + c15] = accB[q] + bv;
  }
}

extern "C" void kernel_launch(void* const* d_in, const int* in_sizes, int n_in,
                              void* d_out, int out_size, void* d_ws, size_t ws_size,
                              hipStream_t stream) {
  const float* x     = (const float*)d_in[0];
  const int*   adj   = (const int*)d_in[1];
  const float* W     = (const float*)d_in[2];
  const float* a_src = (const float*)d_in[3];
  const float* a_tgt = (const float*)d_in[4];
  const float* bias  = (const float*)d_in[5];
  char* ws = (char*)d_ws;
  unsigned short* WhT    = (unsigned short*)ws;         // 4 MB
  float*        fs     = (float*)(ws + 4194304);        // 64 KB
  float*        ft     = (float*)(ws + 4259840);        // 64 KB
  float*        mbpart = (float*)(ws + 4325376);        // 1 KB
  float* hout = (float*)d_out;                          // [B][D][F]
  float* attn = hout + (size_t)BB * DD * FF;            // [B][D][D]
  kA<<<256, 256, 0, stream>>>(x, W, a_src, a_tgt, WhT, fs, ft, mbpart);
  kF<<<512, 512, 0, stream>>>(adj, fs, ft, mbpart, WhT, bias, hout, attn);
}

// Round 8
// 275.201 us; speedup vs baseline: 1.6444x; 1.4506x over previous
//
#include <hip/hip_runtime.h>

#define BB 4
#define DD 4096
#define FF 128
#define SLOPE 0.2f

typedef float f32x4 __attribute__((ext_vector_type(4)));
typedef int   i32x4 __attribute__((ext_vector_type(4)));
typedef short bf16x8 __attribute__((ext_vector_type(8)));

// LDS-only barrier: ds_writes visible across waves, but global loads/stores
// stay in flight (no vmcnt drain, unlike __syncthreads()).
#define SOFT_BARRIER() do { \
  asm volatile("s_waitcnt lgkmcnt(0)" ::: "memory"); \
  __builtin_amdgcn_s_barrier(); \
} while (0)

__device__ __forceinline__ unsigned short f2bf(float v) {
  union { float f; unsigned u; } c; c.f = v;
  unsigned r = c.u + 0x7FFFu + ((c.u >> 16) & 1u);
  return (unsigned short)(r >> 16);
}

// Kernel A: Wh = x@W (f32 regs) -> WhT bf16 [B][F][D]; fs, ft (f32);
// mbpart[wg] = max(0, max over this wg's 64 rows of ft)  (no memset needed)
__global__ __launch_bounds__(256) void kA(
    const float* __restrict__ x, const float* __restrict__ W,
    const float* __restrict__ a_src, const float* __restrict__ a_tgt,
    unsigned short* __restrict__ WhT, float* __restrict__ fs,
    float* __restrict__ ft, float* __restrict__ mbpart)
{
  __shared__ __align__(16) float Ws[128 * 128];
  __shared__ __align__(16) float xs[64 * 128];     // reused as reduction scratch
  __shared__ unsigned short st[128 * 66];
  const int t = threadIdx.x;
  const int wg = blockIdx.x;            // 256 wgs x 64 rows
  const int row0 = wg * 64;             // flat row in [0, B*D)
  const int b = row0 / DD;
  const int i_in_b = row0 % DD;

  for (int i = t * 4; i < 128 * 128; i += 1024)
    *(float4*)&Ws[i] = *(const float4*)&W[i];
  for (int i = t * 4; i < 64 * 128; i += 1024)
    *(float4*)&xs[i] = *(const float4*)&x[(size_t)row0 * FF + i];
  __syncthreads();

  const int fg = t & 31, rg = t >> 5;
  const int f0 = fg * 4, r0 = rg * 8;
  float acc[8][4];
  #pragma unroll
  for (int a = 0; a < 8; ++a) acc[a][0] = acc[a][1] = acc[a][2] = acc[a][3] = 0.f;
  for (int k = 0; k < 128; ++k) {
    float4 wq = *(const float4*)&Ws[k * 128 + f0];
    #pragma unroll
    for (int rr = 0; rr < 8; ++rr) {
      float xv = xs[(r0 + rr) * 128 + k];
      acc[rr][0] += xv * wq.x; acc[rr][1] += xv * wq.y;
      acc[rr][2] += xv * wq.z; acc[rr][3] += xv * wq.w;
    }
  }
  __syncthreads();   // done reading xs; reuse as reduction scratch
  float* red_s = xs;             // [64][33]
  float* red_t = xs + 64 * 33;   // [64][33]
  float4 as4 = *(const float4*)&a_src[f0];
  float4 at4 = *(const float4*)&a_tgt[f0];
  #pragma unroll
  for (int rr = 0; rr < 8; ++rr) {
    float ps = acc[rr][0]*as4.x + acc[rr][1]*as4.y + acc[rr][2]*as4.z + acc[rr][3]*as4.w;
    float pt = acc[rr][0]*at4.x + acc[rr][1]*at4.y + acc[rr][2]*at4.z + acc[rr][3]*at4.w;
    red_s[(r0 + rr) * 33 + fg] = ps;
    red_t[(r0 + rr) * 33 + fg] = pt;
    st[(f0 + 0) * 66 + r0 + rr] = f2bf(acc[rr][0]);
    st[(f0 + 1) * 66 + r0 + rr] = f2bf(acc[rr][1]);
    st[(f0 + 2) * 66 + r0 + rr] = f2bf(acc[rr][2]);
    st[(f0 + 3) * 66 + r0 + rr] = f2bf(acc[rr][3]);
  }
  __syncthreads();
  if (t < 64) {
    float s = 0.f, tt = 0.f;
    #pragma unroll
    for (int q = 0; q < 32; ++q) { s += red_s[t * 33 + q]; tt += red_t[t * 33 + q]; }
    fs[row0 + t] = s;
    ft[row0 + t] = tt;
    float m = fmaxf(0.f, tt);
    #pragma unroll
    for (int s2 = 1; s2 < 64; s2 <<= 1) m = fmaxf(m, __shfl_xor(m, s2));
    if (t == 0) mbpart[wg] = m;        // unconditional write: no init required
  }
  // WhT bf16 writeout (coalesced per 64-wide row chunks)
  for (int p = 0; p < 32; ++p) {
    int idx = p * 256 + t;
    int f = idx >> 6, rl = idx & 63;
    WhT[((size_t)b * FF + f) * DD + i_in_b + rl] = st[f * 66 + rl];
  }
}

// Kernel F (fused): 32 rows/wg, 8 waves, 512 wgs (2 wg/CU).
// Pass 1: 2-deep ping-pong batched adj stream (8 i32x4 in flight per batch).
// Pass 2: 16-chunk pipeline, soft barriers, double-buffered B-prefetch.
__global__ __launch_bounds__(512, 4) void kF(
    const int* __restrict__ adj, const float* __restrict__ fs,
    const float* __restrict__ ft, const float* __restrict__ mbpart,
    const unsigned short* __restrict__ WhT, const float* __restrict__ bias,
    float* __restrict__ hout, float* __restrict__ attn)
{
  __shared__ __align__(16) unsigned short p_lds[2][32 * 256];  // 32 KB, XOR-swizzled
  __shared__ __align__(16) unsigned int mlds[32 * 128];        // 16 KB row bitmasks
  const int t = threadIdx.x;
  const int w = t >> 6, l = t & 63;
  const int hw = blockIdx.x;
  const int bid = (hw & 7) * 64 + (hw >> 3);   // bijective XCD swizzle (nwg=512)
  const int b = bid >> 7;
  const int i0 = (bid & 127) << 5;             // 32 rows per wg
  // per-batch ft upper bound from kA partials
  float mbv = mbpart[b * 64 + l];
  #pragma unroll
  for (int s = 1; s < 64; s <<= 1) mbv = fmaxf(mbv, __shfl_xor(mbv, s));
  const int rbase = 4 * w;                     // wave owns rows rbase..rbase+3
  float fsr[4], Mr[4];
  #pragma unroll
  for (int m = 0; m < 4; ++m) {
    fsr[m] = fs[b * DD + i0 + rbase + m];
    Mr[m] = fmaxf(0.f, fsr[m] + mbv);
  }

  // ---- Pass 1: stream 4 adj rows, 2-deep pipelined batches ----
  const int* ap[4];
  #pragma unroll
  for (int m = 0; m < 4; ++m)
    ap[m] = adj + (size_t)(b * DD + i0 + rbase + m) * DD + l * 64;
  const float* ftl = ft + (size_t)b * DD + l * 64;
  float sum[4] = {0.f, 0.f, 0.f, 0.f};
  unsigned lo[4] = {0u, 0u, 0u, 0u}, hi[4] = {0u, 0u, 0u, 0u};

  auto p1_load = [&](i32x4 (&buf)[4][2], int q) {
    #pragma unroll
    for (int m = 0; m < 4; ++m) {
      buf[m][0] = *(const i32x4*)(ap[m] + q * 8);
      buf[m][1] = *(const i32x4*)(ap[m] + q * 8 + 4);
    }
  };
  auto p1_cons = [&](i32x4 (&buf)[4][2], int q) {
    #pragma unroll
    for (int u = 0; u < 2; ++u) {
      const int o = q * 8 + u * 4;        // compile-time in unrolled context
      float4 f = *(const float4*)(ftl + o);
      #pragma unroll
      for (int m = 0; m < 4; ++m) {
        i32x4 a = buf[m][u];
        float e;
        e = fsr[m] + f.x; e = e > 0.f ? e : SLOPE * e; e = a.x ? e : 0.f; sum[m] += __expf(e - Mr[m]);
        e = fsr[m] + f.y; e = e > 0.f ? e : SLOPE * e; e = a.y ? e : 0.f; sum[m] += __expf(e - Mr[m]);
        e = fsr[m] + f.z; e = e > 0.f ? e : SLOPE * e; e = a.z ? e : 0.f; sum[m] += __expf(e - Mr[m]);
        e = fsr[m] + f.w; e = e > 0.f ? e : SLOPE * e; e = a.w ? e : 0.f; sum[m] += __expf(e - Mr[m]);
        unsigned pack = (a.x ? 1u : 0u) | (a.y ? 2u : 0u) | (a.z ? 4u : 0u) | (a.w ? 8u : 0u);
        if (o < 32) lo[m] |= pack << o; else hi[m] |= pack << (o - 32);
      }
    }
  };

  i32x4 bA[4][2], bB[4][2];
  p1_load(bA, 0);
  p1_load(bB, 1);
  #pragma unroll
  for (int q = 0; q < 8; q += 2) {
    p1_cons(bA, q);
    if (q + 2 < 8) p1_load(bA, q + 2);
    p1_cons(bB, q + 1);
    if (q + 3 < 8) p1_load(bB, q + 3);
  }

  #pragma unroll
  for (int m = 0; m < 4; ++m) {
    uint2 mv; mv.x = lo[m]; mv.y = hi[m];
    *(uint2*)&mlds[(rbase + m) * 128 + l * 2] = mv;
  }
  float inv[4];
  #pragma unroll
  for (int m = 0; m < 4; ++m) {
    #pragma unroll
    for (int s = 1; s < 64; s <<= 1) sum[m] += __shfl_xor(sum[m], s);
    inv[m] = 1.0f / sum[m];
  }

  // ---- Pass 2: 16-chunk pipeline (soft barriers, B double-buffered) ----
  const float* ftb = ft + (size_t)b * DD;
  float* arow[4];
  unsigned o_[4], wb_[4];
  const int jl = l * 4;
  const unsigned mshift = (unsigned)(jl & 31);
  #pragma unroll
  for (int m = 0; m < 4; ++m) {
    const int r = rbase + m;
    arow[m] = attn + (size_t)b * DD * DD + (size_t)(i0 + r) * DD;
    o_[m] = (((unsigned)r * 512u) + (unsigned)jl * 2u) ^ ((unsigned)(r & 7) << 4);
    wb_[m] = (unsigned)r * 128u + (unsigned)(jl >> 5);
  }
  const int f0 = w * 16;
  const int c15 = l & 15;
  const int kg = l >> 4;
  const unsigned abase = (unsigned)c15 * 512u + (unsigned)kg * 16u;
  const unsigned asw = (unsigned)(c15 & 7) << 4;
  const unsigned short* wrow = WhT + ((size_t)b * FF + f0 + c15) * DD + kg * 8;
  f32x4 accA = {0.f, 0.f, 0.f, 0.f}, accB = {0.f, 0.f, 0.f, 0.f};

  bf16x8 BvA[8], BvB[8];
  #pragma unroll
  for (int u = 0; u < 8; ++u)
    BvA[u] = *(const bf16x8*)&wrow[(size_t)u * 32];

#define CHUNK_BODY(CC, BCUR, BNXT, CB) do { \
    const int c_ = (CC); \
    const int j_ = c_ * 256 + jl; \
    /* issue next chunk's B early: stays in flight across soft barrier */ \
    _Pragma("unroll") \
    for (int u = 0; u < 8; ++u) \
      BNXT[u] = *(const bf16x8*)&wrow[(size_t)((((c_) + 1) & 15) * 8 + u) * 32]; \
    float4 f4_ = *(const float4*)(ftb + j_); \
    _Pragma("unroll") \
    for (int m = 0; m < 4; ++m) { \
      unsigned n_ = (mlds[wb_[m] + (unsigned)c_ * 8u] >> mshift) & 0xFu; \
      float e_, p0_, p1_, p2_, p3_; \
      e_ = fsr[m] + f4_.x; e_ = e_ > 0.f ? e_ : SLOPE * e_; e_ = (n_ & 1u) ? e_ : 0.f; p0_ = __expf(e_ - Mr[m]) * inv[m]; \
      e_ = fsr[m] + f4_.y; e_ = e_ > 0.f ? e_ : SLOPE * e_; e_ = (n_ & 2u) ? e_ : 0.f; p1_ = __expf(e_ - Mr[m]) * inv[m]; \
      e_ = fsr[m] + f4_.z; e_ = e_ > 0.f ? e_ : SLOPE * e_; e_ = (n_ & 4u) ? e_ : 0.f; p2_ = __expf(e_ - Mr[m]) * inv[m]; \
      e_ = fsr[m] + f4_.w; e_ = e_ > 0.f ? e_ : SLOPE * e_; e_ = (n_ & 8u) ? e_ : 0.f; p3_ = __expf(e_ - Mr[m]) * inv[m]; \
      f32x4 v_; v_.x = p0_; v_.y = p1_; v_.z = p2_; v_.w = p3_; \
      *(f32x4*)(arow[m] + j_) = v_; \
      ushort4 qv_; qv_.x = f2bf(p0_); qv_.y = f2bf(p1_); qv_.z = f2bf(p2_); qv_.w = f2bf(p3_); \
      *(ushort4*)((char*)&p_lds[CB][0] + o_[m]) = qv_; \
    } \
    SOFT_BARRIER(); \
    _Pragma("unroll") \
    for (int u = 0; u < 8; ++u) { \
      unsigned ao_ = (abase + (unsigned)u * 64u) ^ asw; \
      bf16x8 A0_ = *(const bf16x8*)((const char*)&p_lds[CB][0] + ao_); \
      bf16x8 A1_ = *(const bf16x8*)((const char*)&p_lds[CB][0] + ao_ + 8192u); \
      accA = __builtin_amdgcn_mfma_f32_16x16x32_bf16(A0_, BCUR[u], accA, 0, 0, 0); \
      accB = __builtin_amdgcn_mfma_f32_16x16x32_bf16(A1_, BCUR[u], accB, 0, 0, 0); \
    } \
  } while (0)

  for (int cc = 0; cc < 8; ++cc) {
    CHUNK_BODY(cc * 2,     BvA, BvB, 0);
    CHUNK_BODY(cc * 2 + 1, BvB, BvA, 1);
  }
#undef CHUNK_BODY

  const float bv = bias[f0 + c15];
  #pragma unroll
  for (int q = 0; q < 4; ++q) {
    int orow = kg * 4 + q;       // C/D: row = (lane>>4)*4 + reg
    hout[((size_t)b * DD + i0 + orow) * FF + f0 + c15] = accA[q] + bv;
    hout[((size_t)b * DD + i0 + 16 + orow) * FF + f0 + c15] = accB[q] + bv;
  }
}

extern "C" void kernel_launch(void* const* d_in, const int* in_sizes, int n_in,
                              void* d_out, int out_size, void* d_ws, size_t ws_size,
                              hipStream_t stream) {
  const float* x     = (const float*)d_in[0];
  const int*   adj   = (const int*)d_in[1];
  const float* W     = (const float*)d_in[2];
  const float* a_src = (const float*)d_in[3];
  const float* a_tgt = (const float*)d_in[4];
  const float* bias  = (const float*)d_in[5];
  char* ws = (char*)d_ws;
  unsigned short* WhT    = (unsigned short*)ws;         // 4 MB
  float*        fs     = (float*)(ws + 4194304);        // 64 KB
  float*        ft     = (float*)(ws + 4259840);        // 64 KB
  float*        mbpart = (float*)(ws + 4325376);        // 1 KB
  float* hout = (float*)d_out;                          // [B][D][F]
  float* attn = hout + (size_t)BB * DD * FF;            // [B][D][D]
  kA<<<256, 256, 0, stream>>>(x, W, a_src, a_tgt, WhT, fs, ft, mbpart);
  kF<<<512, 512, 0, stream>>>(adj, fs, ft, mbpart, WhT, bias, hout, attn);
}